// Round 11
// baseline (507.463 us; speedup 1.0000x reference)
//
#include <hip/hip_runtime.h>
#include <math.h>

#define N_ 4096
#define V_ 4
#define C_ 256

typedef __attribute__((ext_vector_type(8))) short bf16x8;
typedef __attribute__((ext_vector_type(4))) float f32x4;
typedef unsigned long long u64;

// ---------------- workspace byte offsets ----------------
#define OFF_R      0ull            // f32 R[v][n][c]          16MB
#define OFF_DNHI   16777216ull     // bf16                     8MB
#define OFF_DNLO   25165824ull     // bf16                     8MB
#define OFF_SFT    33554432ull     // fp8 sfT[v][c][n]         4MB
#define OFF_E      37748736ull     // fp8 E slots x3          48MB
#define OFF_ET     88080384ull     // fp8 ET slots x3         48MB
#define OFF_WTH    138412032ull    // bf16 WT hi 256x256     128KB
#define OFF_WTL    138543104ull
#define OFF_ROWPK  138674176ull    // u64 rowPk[6][4096]     192KB
#define OFF_COLPK  138870784ull    // u64 colPk[6][4096]
#define OFF_ROWSM  139067392ull    // f32 rowSm[6][4096]      96KB
#define OFF_COLSM  139165696ull
#define OFF_RELWT  139264000ull    // f32 16x256
#define OFF_SQ     139280384ull
#define OFF_CNT    139280448ull

__device__ __forceinline__ unsigned short f2bf(float x) {
    unsigned int u = __float_as_uint(x);
    u += 0x7fffu + ((u >> 16) & 1u);
    return (unsigned short)(u >> 16);
}
__device__ __forceinline__ float bf2f(unsigned short h) {
    return __uint_as_float(((unsigned int)h) << 16);
}
__device__ __forceinline__ f32x4 mfma16(bf16x8 a, bf16x8 b, f32x4 c) {
    return __builtin_amdgcn_mfma_f32_16x16x32_bf16(a, b, c, 0, 0, 0);
}
__device__ __forceinline__ unsigned int pk4fp8(float x0, float x1, float x2, float x3) {
    int w = 0;
    w = __builtin_amdgcn_cvt_pk_fp8_f32(x0, x1, w, false);
    w = __builtin_amdgcn_cvt_pk_fp8_f32(x2, x3, w, true);
    return (unsigned int)w;
}

// ---- fused preprocessing: one launch replaces 5 (normalize/sfT/wrecT/relwt/zero).
//      blocks: [0,16384) normalize | [16384,17408) sfT | [17408,17424) wrecT |
//              [17424,17440) relwt | [17440,17536) zero ----
__global__ void fused_pre_k(const float* __restrict__ desc,
                            unsigned short* __restrict__ dnh, unsigned short* __restrict__ dnl,
                            const float* __restrict__ W, unsigned short* __restrict__ WTh,
                            unsigned short* __restrict__ WTl,
                            const float* __restrict__ sf, unsigned char* __restrict__ sf8T,
                            const float* __restrict__ T, const float* __restrict__ WT,
                            float* __restrict__ relwt,
                            u64* rowPk, u64* colPk, float* rowSm, float* colSm,
                            float* sq, int* cnt) {
    __shared__ float shf[64 * 65];    // 16.25KB: Tt for sfT/wrecT; first 256 = red for normalize
    int b = blockIdx.x;
    int t = threadIdx.x;
    if (b < 16384) {
        // ---- normalize + bf16 hi/lo split: dn[v][n][c] ----
        int row = b;                   // n*V + v
        int n = row >> 2, v = row & 3;
        float x = desc[(size_t)row * C_ + t];
        shf[t] = x * x;
        __syncthreads();
        for (int s = 128; s > 0; s >>= 1) {
            if (t < s) shf[t] += shf[t + s];
            __syncthreads();
        }
        float inv = 1.0f / fmaxf(sqrtf(shf[0]), 1e-12f);
        float y = x * inv;
        size_t o = ((size_t)v * N_ + n) * C_ + t;
        unsigned short h = f2bf(y);
        dnh[o] = h;
        dnl[o] = f2bf(y - bf2f(h));
    } else if (b < 17408) {
        // ---- sf8T[v][c][n] = fp8(sf[n][v][c]) ----
        int idx = b - 16384;
        int n0 = (idx & 63) * 64, c0 = ((idx >> 6) & 3) * 64, v = idx >> 8;
        int nr = t >> 2, cq = (t & 3) * 16;
        const float* src = sf + ((size_t)(n0 + nr) * V_ + v) * C_ + c0 + cq;
        for (int u = 0; u < 16; ++u) shf[(cq + u) * 65 + nr] = src[u];
        __syncthreads();
        int cr = t >> 2, nq = (t & 3) * 16;
        unsigned int wb[4];
#pragma unroll
        for (int g = 0; g < 4; ++g) {
            const float* p = shf + cr * 65 + nq + g * 4;
            wb[g] = pk4fp8(p[0], p[1], p[2], p[3]);
        }
        unsigned char* dst = sf8T + ((size_t)v * C_ + c0 + cr) * N_ + n0 + nq;
        *(uint4*)dst = make_uint4(wb[0], wb[1], wb[2], wb[3]);
    } else if (b < 17424) {
        // ---- WT[c][k] = W_rec[k][c], hi/lo bf16 split ----
        int idx = b - 17408;
        int k0 = (idx & 3) * 64, c0 = (idx >> 2) * 64;
        int kr = t >> 2, cq = (t & 3) * 16;
        const float* src = W + (size_t)(k0 + kr) * C_ + c0 + cq;
        for (int u = 0; u < 16; ++u) shf[(cq + u) * 65 + kr] = src[u];
        __syncthreads();
        int cr = t >> 2, kq = (t & 3) * 16;
        unsigned short th[16] __attribute__((aligned(16)));
        unsigned short tl[16] __attribute__((aligned(16)));
        for (int u = 0; u < 16; ++u) {
            float x = shf[cr * 65 + kq + u];
            unsigned short h = f2bf(x);
            th[u] = h; tl[u] = f2bf(x - bf2f(h));
        }
        size_t o = (size_t)(c0 + cr) * C_ + k0 + kq;
        *(uint4*)(WTh + o) = *(const uint4*)th;
        *(uint4*)(WTh + o + 8) = *(const uint4*)(th + 8);
        *(uint4*)(WTl + o) = *(const uint4*)tl;
        *(uint4*)(WTl + o + 8) = *(const uint4*)(tl + 8);
    } else if (b < 17440) {
        // ---- relWT[p][c], p = i*4+j ----
        int p = b - 17424; int i = p >> 2, j = p & 3;
        if (i == j) return;
        float acc = 0.f;
        for (int k = 0; k < 16; ++k) acc += T[i * 16 + k] * WT[(size_t)k * C_ + t];
        for (int k = 0; k < 16; ++k) acc += T[j * 16 + k] * WT[(size_t)(16 + k) * C_ + t];
        relwt[(size_t)p * C_ + t] = acc;
    } else {
        // ---- zero stats (all 6 slots) + pair accumulators ----
        int idx = (b - 17440) * 256 + t;   // 0..24575
        rowPk[idx] = 0ull; colPk[idx] = 0ull;
        rowSm[idx] = 0.f;  colSm[idx] = 0.f;
        if (idx < 16) { sq[idx] = 0.f; cnt[idx] = 0; }
    }
}

// ---- R = dn @ W_rec via split-bf16 MFMA; block 128x128, wave 64x64 ----
__global__ __launch_bounds__(256) void rmatmul_k(
    const unsigned short* __restrict__ Ah, const unsigned short* __restrict__ Al,
    const unsigned short* __restrict__ Bh, const unsigned short* __restrict__ Bl,
    float* __restrict__ R) {
    __shared__ unsigned short smem[4 * 128 * 40];
    unsigned short* sAh = smem;
    unsigned short* sAl = sAh + 128 * 40;
    unsigned short* sBh = sAl + 128 * 40;
    unsigned short* sBl = sBh + 128 * 40;
    int tid = threadIdx.x;
    int c0 = blockIdx.x * 128, m0 = blockIdx.y * 128;
    int w = tid >> 6, l = tid & 63, wm = w & 1, wn = w >> 1;
    int mr = l & 15, q = l >> 4;
    f32x4 acc[4][4];
#pragma unroll
    for (int a = 0; a < 4; ++a)
#pragma unroll
        for (int b = 0; b < 4; ++b)
#pragma unroll
            for (int u = 0; u < 4; ++u) acc[a][b][u] = 0.f;
    int r = tid >> 1, h = (tid & 1) * 16;
    for (int k0 = 0; k0 < C_; k0 += 32) {
        size_t ga = (size_t)(m0 + r) * C_ + k0 + h;
        size_t gb = (size_t)(c0 + r) * C_ + k0 + h;
        uint4 a0 = *(const uint4*)(Ah + ga);
        uint4 a1 = *(const uint4*)(Ah + ga + 8);
        uint4 a2 = *(const uint4*)(Al + ga);
        uint4 a3 = *(const uint4*)(Al + ga + 8);
        uint4 b0 = *(const uint4*)(Bh + gb);
        uint4 b1 = *(const uint4*)(Bh + gb + 8);
        uint4 b2 = *(const uint4*)(Bl + gb);
        uint4 b3 = *(const uint4*)(Bl + gb + 8);
        *(uint4*)(sAh + r * 40 + h)     = a0;
        *(uint4*)(sAh + r * 40 + h + 8) = a1;
        *(uint4*)(sAl + r * 40 + h)     = a2;
        *(uint4*)(sAl + r * 40 + h + 8) = a3;
        *(uint4*)(sBh + r * 40 + h)     = b0;
        *(uint4*)(sBh + r * 40 + h + 8) = b1;
        *(uint4*)(sBl + r * 40 + h)     = b2;
        *(uint4*)(sBl + r * 40 + h + 8) = b3;
        __syncthreads();
        bf16x8 fah[4], fal[4], fbh[4], fbl[4];
#pragma unroll
        for (int ti = 0; ti < 4; ++ti) {
            int row = wm * 64 + ti * 16 + mr;
            fah[ti] = *(const bf16x8*)(sAh + row * 40 + q * 8);
            fal[ti] = *(const bf16x8*)(sAl + row * 40 + q * 8);
        }
#pragma unroll
        for (int tj = 0; tj < 4; ++tj) {
            int row = wn * 64 + tj * 16 + mr;
            fbh[tj] = *(const bf16x8*)(sBh + row * 40 + q * 8);
            fbl[tj] = *(const bf16x8*)(sBl + row * 40 + q * 8);
        }
#pragma unroll
        for (int ti = 0; ti < 4; ++ti)
#pragma unroll
            for (int tj = 0; tj < 4; ++tj) acc[ti][tj] = mfma16(fah[ti], fbh[tj], acc[ti][tj]);
#pragma unroll
        for (int ti = 0; ti < 4; ++ti)
#pragma unroll
            for (int tj = 0; tj < 4; ++tj) acc[ti][tj] = mfma16(fah[ti], fbl[tj], acc[ti][tj]);
#pragma unroll
        for (int ti = 0; ti < 4; ++ti)
#pragma unroll
            for (int tj = 0; tj < 4; ++tj) acc[ti][tj] = mfma16(fal[ti], fbh[tj], acc[ti][tj]);
        __syncthreads();
    }
#pragma unroll
    for (int ti = 0; ti < 4; ++ti)
#pragma unroll
        for (int tj = 0; tj < 4; ++tj) {
            int c = c0 + wn * 64 + tj * 16 + mr;
#pragma unroll
            for (int rg = 0; rg < 4; ++rg) {
                int m = m0 + wm * 64 + ti * 16 + q * 4 + rg;
                R[(size_t)m * C_ + c] = acc[ti][tj][rg];
            }
        }
}

// ---- sim: 64x64 tile, split-bf16 3-term, reg-prefetched staging,
//      exp-once, fp8 E/ET. Stats fused into pack passes; partial reduce via
//      4-lane shuffles. grid (64, 64, 3) ----
__global__ __launch_bounds__(256) void sim_mfma_k(
    const unsigned short* __restrict__ dnh, const unsigned short* __restrict__ dnl,
    int ipack, int jpack, unsigned char* __restrict__ E8b, unsigned char* __restrict__ ET8b,
    u64* __restrict__ rowPkB, float* __restrict__ rowSmB,
    u64* __restrict__ colPkB, float* __restrict__ colSmB, int slotBase) {
    __shared__ unsigned char smem[36864];
    unsigned short* sAh = (unsigned short*)smem;          // [64][72]
    unsigned short* sAl = sAh + 64 * 72;
    unsigned short* sBh = sAl + 64 * 72;
    unsigned short* sBl = sBh + 64 * 72;
    float* S = (float*)smem;                               // [64][65] alias, holds expS

    int zp = blockIdx.z;
    int iv = (ipack >> (8 * zp)) & 15;
    int jv = (jpack >> (8 * zp)) & 15;
    const unsigned short* Ahi = dnh + (size_t)iv * N_ * C_;
    const unsigned short* Alo = dnl + (size_t)iv * N_ * C_;
    const unsigned short* Bhi = dnh + (size_t)jv * N_ * C_;
    const unsigned short* Blo = dnl + (size_t)jv * N_ * C_;
    unsigned char* E8  = E8b  + (size_t)zp * N_ * N_;
    unsigned char* ET8 = ET8b + (size_t)zp * N_ * N_;
    int slot = slotBase + zp;
    u64*   rowPk = rowPkB + (size_t)slot * N_;
    float* rowSm = rowSmB + (size_t)slot * N_;
    u64*   colPk = colPkB + (size_t)slot * N_;
    float* colSm = colSmB + (size_t)slot * N_;

    int tid = threadIdx.x;
    int m0 = blockIdx.y * 64, n0 = blockIdx.x * 64;
    int w = tid >> 6, l = tid & 63;
    int wm = w & 1, wn = w >> 1;
    int mr = l & 15, q = l >> 4;

    f32x4 acc[2][2];
#pragma unroll
    for (int a = 0; a < 2; ++a)
#pragma unroll
        for (int b = 0; b < 2; ++b)
#pragma unroll
            for (int u = 0; u < 4; ++u) acc[a][b][u] = 0.f;

    int r = tid >> 2;
    int k8 = (tid & 3) * 8;
    const unsigned short* gAh = Ahi + (size_t)(m0 + r) * C_ + k8;
    const unsigned short* gAl = Alo + (size_t)(m0 + r) * C_ + k8;
    const unsigned short* gBh = Bhi + (size_t)(n0 + r) * C_ + k8;
    const unsigned short* gBl = Blo + (size_t)(n0 + r) * C_ + k8;

    uint4 a0 = *(const uint4*)(gAh);
    uint4 a1 = *(const uint4*)(gAh + 32);
    uint4 a2 = *(const uint4*)(gAl);
    uint4 a3 = *(const uint4*)(gAl + 32);
    uint4 b0 = *(const uint4*)(gBh);
    uint4 b1 = *(const uint4*)(gBh + 32);
    uint4 b2 = *(const uint4*)(gBl);
    uint4 b3 = *(const uint4*)(gBl + 32);

    for (int k0 = 0; k0 < C_; k0 += 64) {
        *(uint4*)(sAh + r * 72 + k8)      = a0;
        *(uint4*)(sAh + r * 72 + k8 + 32) = a1;
        *(uint4*)(sAl + r * 72 + k8)      = a2;
        *(uint4*)(sAl + r * 72 + k8 + 32) = a3;
        *(uint4*)(sBh + r * 72 + k8)      = b0;
        *(uint4*)(sBh + r * 72 + k8 + 32) = b1;
        *(uint4*)(sBl + r * 72 + k8)      = b2;
        *(uint4*)(sBl + r * 72 + k8 + 32) = b3;
        __syncthreads();
        int kn = k0 + 64;
        if (kn < C_) {      // prefetch next K-chunk; vmcnt awaited at next staging write
            a0 = *(const uint4*)(gAh + kn);
            a1 = *(const uint4*)(gAh + kn + 32);
            a2 = *(const uint4*)(gAl + kn);
            a3 = *(const uint4*)(gAl + kn + 32);
            b0 = *(const uint4*)(gBh + kn);
            b1 = *(const uint4*)(gBh + kn + 32);
            b2 = *(const uint4*)(gBl + kn);
            b3 = *(const uint4*)(gBl + kn + 32);
        }
#pragma unroll
        for (int ks = 0; ks < 64; ks += 32) {
            bf16x8 ah[2], al[2], bh[2], bl[2];
#pragma unroll
            for (int ti = 0; ti < 2; ++ti) {
                int mrow = wm * 32 + ti * 16 + mr;
                ah[ti] = *(const bf16x8*)(sAh + mrow * 72 + ks + q * 8);
                al[ti] = *(const bf16x8*)(sAl + mrow * 72 + ks + q * 8);
            }
#pragma unroll
            for (int tj = 0; tj < 2; ++tj) {
                int nrow = wn * 32 + tj * 16 + mr;
                bh[tj] = *(const bf16x8*)(sBh + nrow * 72 + ks + q * 8);
                bl[tj] = *(const bf16x8*)(sBl + nrow * 72 + ks + q * 8);
            }
#pragma unroll
            for (int ti = 0; ti < 2; ++ti)
#pragma unroll
                for (int tj = 0; tj < 2; ++tj) {
                    acc[ti][tj] = mfma16(ah[ti], bh[tj], acc[ti][tj]);
                    acc[ti][tj] = mfma16(ah[ti], bl[tj], acc[ti][tj]);
                    acc[ti][tj] = mfma16(al[ti], bh[tj], acc[ti][tj]);
                }
        }
        __syncthreads();
    }

    // ---- epilogue: exp once into LDS ----
#pragma unroll
    for (int ti = 0; ti < 2; ++ti)
#pragma unroll
        for (int tj = 0; tj < 2; ++tj)
#pragma unroll
            for (int rg = 0; rg < 4; ++rg)
                S[(wm * 32 + ti * 16 + q * 4 + rg) * 65 + wn * 32 + tj * 16 + mr] =
                    __expf(acc[ti][tj][rg]);
    __syncthreads();

    // FUSED pass 1: E store (fp8, row-major) + row max/argmax/sum.
    {
        int rr = tid >> 2, cq = (tid & 3) * 16;
        const float* p = S + rr * 65 + cq;
        float mx = -1e30f; int ag = 0; float sm = 0.f;
        unsigned int wb[4];
#pragma unroll
        for (int g = 0; g < 4; ++g) {
            float f0 = p[g * 4 + 0], f1 = p[g * 4 + 1];
            float f2 = p[g * 4 + 2], f3 = p[g * 4 + 3];
            sm += (f0 + f1) + (f2 + f3);
            if (f0 > mx) { mx = f0; ag = cq + g * 4 + 0; }
            if (f1 > mx) { mx = f1; ag = cq + g * 4 + 1; }
            if (f2 > mx) { mx = f2; ag = cq + g * 4 + 2; }
            if (f3 > mx) { mx = f3; ag = cq + g * 4 + 3; }
            wb[g] = pk4fp8(f0, f1, f2, f3);
        }
        *(uint4*)(E8 + (size_t)(m0 + rr) * N_ + n0 + cq) = make_uint4(wb[0], wb[1], wb[2], wb[3]);
#pragma unroll
        for (int d = 1; d <= 2; d <<= 1) {
            float omx = __shfl_xor(mx, d);
            int   oag = __shfl_xor(ag, d);
            float osm = __shfl_xor(sm, d);
            sm += osm;
            if (omx > mx || (omx == mx && oag < ag)) { mx = omx; ag = oag; }
        }
        if ((tid & 3) == 0) {
            u64 pk = ((u64)__float_as_uint(mx) << 32) | (u64)(0xFFFFFFFFu - (unsigned)(n0 + ag));
            atomicMax(rowPk + m0 + rr, pk);
            atomicAdd(rowSm + m0 + rr, sm);
        }
    }
    // FUSED pass 2: ET store (fp8, row-major in n) + col max/argmax/sum.
    {
        int cc = tid >> 2, mq = (tid & 3) * 16;
        float mx = -1e30f; int ag = 0; float sm = 0.f;
        unsigned int wb[4];
#pragma unroll
        for (int g = 0; g < 4; ++g) {
            float f0 = S[(mq + g * 4 + 0) * 65 + cc];
            float f1 = S[(mq + g * 4 + 1) * 65 + cc];
            float f2 = S[(mq + g * 4 + 2) * 65 + cc];
            float f3 = S[(mq + g * 4 + 3) * 65 + cc];
            sm += (f0 + f1) + (f2 + f3);
            if (f0 > mx) { mx = f0; ag = mq + g * 4 + 0; }
            if (f1 > mx) { mx = f1; ag = mq + g * 4 + 1; }
            if (f2 > mx) { mx = f2; ag = mq + g * 4 + 2; }
            if (f3 > mx) { mx = f3; ag = mq + g * 4 + 3; }
            wb[g] = pk4fp8(f0, f1, f2, f3);
        }
        *(uint4*)(ET8 + (size_t)(n0 + cc) * N_ + m0 + mq) = make_uint4(wb[0], wb[1], wb[2], wb[3]);
#pragma unroll
        for (int d = 1; d <= 2; d <<= 1) {
            float omx = __shfl_xor(mx, d);
            int   oag = __shfl_xor(ag, d);
            float osm = __shfl_xor(sm, d);
            sm += osm;
            if (omx > mx || (omx == mx && oag < ag)) { mx = omx; ag = oag; }
        }
        if ((tid & 3) == 0) {
            u64 pk = ((u64)__float_as_uint(mx) << 32) | (u64)(0xFFFFFFFFu - (unsigned)(m0 + ag));
            atomicMax(colPk + n0 + cc, pk);
            atomicAdd(colSm + n0 + cc, sm);
        }
    }
}

// ---- pass2 v4: fp8 GEMM 64m x 256c (full c width -> each A panel read ONCE),
//      K-chunk 64, pitch-80 LDS, fused loss. grid (64, 6): bx = mt; by -> d, zp ----
__global__ __launch_bounds__(256) void p2_k(
    const unsigned char* __restrict__ E8b, const unsigned char* __restrict__ ET8b,
    const unsigned char* __restrict__ sf8T, int ipack, int jpack,
    const u64* __restrict__ rowPkB, const float* __restrict__ rowSmB,
    const u64* __restrict__ colPkB, const float* __restrict__ colSmB, int slotBase,
    const float* __restrict__ R, const float* __restrict__ relwt,
    float* __restrict__ pairSq, int* __restrict__ pairCnt) {
    __shared__ unsigned char sA[64 * 80];    // 64 m-rows x 64 k + pad
    __shared__ unsigned char sB[256 * 80];   // 256 c-rows x 64 k + pad (20KB)
    __shared__ float red[256];
    __shared__ int   mutS[64];
    __shared__ float invS[64];
    int tid = threadIdx.x;
    int mt = blockIdx.x;
    int d = blockIdx.y & 1, zp = blockIdx.y >> 1;
    int iv = (ipack >> (8 * zp)) & 15;
    int jv = (jpack >> (8 * zp)) & 15;
    int slot = slotBase + zp;
    const unsigned char* A = (d ? ET8b : E8b) + (size_t)zp * N_ * N_;
    const unsigned char* B = sf8T + (size_t)(d ? iv : jv) * C_ * N_;
    const u64* faPk = (d ? colPkB : rowPkB) + (size_t)slot * N_;
    const u64* baPk = (d ? rowPkB : colPkB) + (size_t)slot * N_;
    const float* sumE = (d ? colSmB : rowSmB) + (size_t)slot * N_;
    const float* Rr = R + (size_t)(d ? jv : iv) * N_ * C_;
    int pid = d ? (jv * 4 + iv) : (iv * 4 + jv);
    int m0 = mt * 64;
    int w = tid >> 6, l = tid & 63, wm = w & 1, wn = w >> 1;
    int mr = l & 15, q = l >> 4;
    if (tid < 64) {
        int y = m0 + tid;
        unsigned faIdx = 0xFFFFFFFFu - (unsigned)(faPk[y] & 0xFFFFFFFFull);
        unsigned baIdx = 0xFFFFFFFFu - (unsigned)(baPk[faIdx] & 0xFFFFFFFFull);
        mutS[tid] = (baIdx == (unsigned)y) ? 1 : 0;
        invS[tid] = 1.0f / sumE[y];
    }
    f32x4 acc[2][8];
#pragma unroll
    for (int a = 0; a < 2; ++a)
#pragma unroll
        for (int b = 0; b < 8; ++b)
#pragma unroll
            for (int u = 0; u < 4; ++u) acc[a][b][u] = 0.f;

    int ra = tid >> 2, ka = (tid & 3) * 16;
    const unsigned char* Arow = A + (size_t)(m0 + ra) * N_ + ka;
    const unsigned char* Brow = B + (size_t)tid * N_;     // thread t owns c-row t (full 64B)
    uint4 pa  = *(const uint4*)(Arow);
    uint4 pb0 = *(const uint4*)(Brow);
    uint4 pb1 = *(const uint4*)(Brow + 16);
    uint4 pb2 = *(const uint4*)(Brow + 32);
    uint4 pb3 = *(const uint4*)(Brow + 48);
    for (int k0 = 0; k0 < N_; k0 += 64) {
        *(uint4*)(sA + ra * 80 + ka)       = pa;
        *(uint4*)(sB + tid * 80)           = pb0;
        *(uint4*)(sB + tid * 80 + 16)      = pb1;
        *(uint4*)(sB + tid * 80 + 32)      = pb2;
        *(uint4*)(sB + tid * 80 + 48)      = pb3;
        __syncthreads();
        int kn = k0 + 64;
        if (kn < N_) {
            pa  = *(const uint4*)(Arow + kn);
            pb0 = *(const uint4*)(Brow + kn);
            pb1 = *(const uint4*)(Brow + kn + 16);
            pb2 = *(const uint4*)(Brow + kn + 32);
            pb3 = *(const uint4*)(Brow + kn + 48);
        }
#pragma unroll
        for (int ksub = 0; ksub < 64; ksub += 32) {
            long af[2], bf[8];
#pragma unroll
            for (int ti = 0; ti < 2; ++ti)
                af[ti] = *(const long*)(sA + (wm * 32 + ti * 16 + mr) * 80 + ksub + q * 8);
#pragma unroll
            for (int tj = 0; tj < 8; ++tj)
                bf[tj] = *(const long*)(sB + (wn * 128 + tj * 16 + mr) * 80 + ksub + q * 8);
#pragma unroll
            for (int ti = 0; ti < 2; ++ti)
#pragma unroll
                for (int tj = 0; tj < 8; ++tj)
                    acc[ti][tj] = __builtin_amdgcn_mfma_f32_16x16x32_fp8_fp8(
                        af[ti], bf[tj], acc[ti][tj], 0, 0, 0);
        }
        __syncthreads();
    }
    const float* rw = relwt + (size_t)pid * C_;
    float local = 0.f;
#pragma unroll
    for (int ti = 0; ti < 2; ++ti)
#pragma unroll
        for (int tj = 0; tj < 8; ++tj) {
            int c = wn * 128 + tj * 16 + mr;
            float rwc = rw[c];
#pragma unroll
            for (int rg = 0; rg < 4; ++rg) {
                int ml = wm * 32 + ti * 16 + q * 4 + rg;
                if (mutS[ml]) {
                    int m = m0 + ml;
                    float soft = acc[ti][tj][rg] * invS[ml];
                    float dv = Rr[(size_t)m * C_ + c] + rwc - soft;
                    local += dv * dv;
                }
            }
        }
    red[tid] = local;
    __syncthreads();
    for (int s = 128; s > 0; s >>= 1) {
        if (tid < s) red[tid] += red[tid + s];
        __syncthreads();
    }
    if (tid == 0) {
        atomicAdd(pairSq + pid, red[0]);
        int cnt = 0;
        for (int u = 0; u < 64; ++u) cnt += mutS[u];
        atomicAdd(pairCnt + pid, cnt);   // each mt block is the unique counter for its rows
    }
}

// ---- final scalar combine ----
__global__ void final_k(const float* __restrict__ sq, const int* __restrict__ cnt,
                        float* __restrict__ out) {
    if (threadIdx.x == 0 && blockIdx.x == 0) {
        float loss = 0.f, count = 0.f;
        for (int p = 0; p < 16; ++p) {
            int i = p >> 2, j = p & 3;
            if (i == j) continue;
            float ns = (float)cnt[p];
            if (ns > 0.f) { loss += sq[p] / fmaxf(ns * (float)C_, 1.0f); count += 1.f; }
        }
        out[0] = (count > 0.f) ? loss / count : 0.f;
    }
}

extern "C" void kernel_launch(void* const* d_in, const int* in_sizes, int n_in,
                              void* d_out, int out_size, void* d_ws, size_t ws_size,
                              hipStream_t stream) {
    const float* desc = (const float*)d_in[0];
    const float* sf   = (const float*)d_in[1];
    const float* T    = (const float*)d_in[2];
    const float* Wrec = (const float*)d_in[3];
    const float* WT   = (const float*)d_in[4];
    float* out = (float*)d_out;
    char* ws = (char*)d_ws;

    float*          R     = (float*)(ws + OFF_R);
    unsigned short* dnh   = (unsigned short*)(ws + OFF_DNHI);
    unsigned short* dnl   = (unsigned short*)(ws + OFF_DNLO);
    unsigned char*  sf8T  = (unsigned char*)(ws + OFF_SFT);
    unsigned char*  E8b   = (unsigned char*)(ws + OFF_E);
    unsigned char*  ET8b  = (unsigned char*)(ws + OFF_ET);
    unsigned short* WTh   = (unsigned short*)(ws + OFF_WTH);
    unsigned short* WTl   = (unsigned short*)(ws + OFF_WTL);
    u64*   rowPk = (u64*)(ws + OFF_ROWPK);
    u64*   colPk = (u64*)(ws + OFF_COLPK);
    float* rowSm = (float*)(ws + OFF_ROWSM);
    float* colSm = (float*)(ws + OFF_COLSM);
    float* relwt = (float*)(ws + OFF_RELWT);
    float* pairSq = (float*)(ws + OFF_SQ);
    int*   pairCnt = (int*)(ws + OFF_CNT);

    // one fused preprocessing launch (was 5)
    fused_pre_k<<<17536, 256, 0, stream>>>(desc, dnh, dnl, Wrec, WTh, WTl,
                                           sf, sf8T, T, WT, relwt,
                                           rowPk, colPk, rowSm, colSm, pairSq, pairCnt);
    rmatmul_k<<<dim3(2, 128), 256, 0, stream>>>(dnh, dnl, WTh, WTl, R);

    // batch 0: pairs (0,1),(0,2),(0,3); batch 1: (1,2),(1,3),(2,3)
    const int ip[2] = { 0 | (0 << 8) | (0 << 16), 1 | (1 << 8) | (2 << 16) };
    const int jp[2] = { 1 | (2 << 8) | (3 << 16), 2 | (3 << 8) | (3 << 16) };
    for (int b = 0; b < 2; ++b) {
        sim_mfma_k<<<dim3(64, 64, 3), 256, 0, stream>>>(
            dnh, dnl, ip[b], jp[b], E8b, ET8b, rowPk, rowSm, colPk, colSm, b * 3);
        p2_k<<<dim3(64, 6), 256, 0, stream>>>(
            E8b, ET8b, sf8T, ip[b], jp[b], rowPk, rowSm, colPk, colSm, b * 3,
            R, relwt, pairSq, pairCnt);
    }
    final_k<<<1, 64, 0, stream>>>(pairSq, pairCnt, out);
}

// Round 12
// 479.607 us; speedup vs baseline: 1.0581x; 1.0581x over previous
//
#include <hip/hip_runtime.h>
#include <math.h>

#define N_ 4096
#define V_ 4
#define C_ 256

typedef __attribute__((ext_vector_type(8))) short bf16x8;
typedef __attribute__((ext_vector_type(4))) float f32x4;
typedef unsigned long long u64;

// ---------------- workspace byte offsets ----------------
#define OFF_R      0ull            // f32 R[v][n][c]          16MB
#define OFF_DNHI   16777216ull     // bf16                     8MB
#define OFF_DNLO   25165824ull     // bf16                     8MB
#define OFF_SFT    33554432ull     // fp8 sfT[v][c][n]         4MB
#define OFF_E      37748736ull     // fp8 E slots x3          48MB
#define OFF_ET     88080384ull     // fp8 ET slots x3         48MB
#define OFF_WTH    138412032ull    // bf16 WT hi 256x256     128KB
#define OFF_WTL    138543104ull
#define OFF_ROWPK  138674176ull    // u64 rowPk[6][4096]     192KB
#define OFF_COLPK  138870784ull    // u64 colPk[6][4096]
#define OFF_ROWSM  139067392ull    // f32 rowSm[6][4096]      96KB
#define OFF_COLSM  139165696ull
#define OFF_RELWT  139264000ull    // f32 16x256
#define OFF_SQ     139280384ull
#define OFF_CNT    139280448ull

__device__ __forceinline__ unsigned short f2bf(float x) {
    unsigned int u = __float_as_uint(x);
    u += 0x7fffu + ((u >> 16) & 1u);
    return (unsigned short)(u >> 16);
}
__device__ __forceinline__ float bf2f(unsigned short h) {
    return __uint_as_float(((unsigned int)h) << 16);
}
__device__ __forceinline__ f32x4 mfma16(bf16x8 a, bf16x8 b, f32x4 c) {
    return __builtin_amdgcn_mfma_f32_16x16x32_bf16(a, b, c, 0, 0, 0);
}
__device__ __forceinline__ unsigned int pk4fp8(float x0, float x1, float x2, float x3) {
    int w = 0;
    w = __builtin_amdgcn_cvt_pk_fp8_f32(x0, x1, w, false);
    w = __builtin_amdgcn_cvt_pk_fp8_f32(x2, x3, w, true);
    return (unsigned int)w;
}

// ---- fused preprocessing: one launch replaces 5 (normalize/sfT/wrecT/relwt/zero).
//      blocks: [0,16384) normalize | [16384,17408) sfT | [17408,17424) wrecT |
//              [17424,17440) relwt | [17440,17536) zero ----
__global__ void fused_pre_k(const float* __restrict__ desc,
                            unsigned short* __restrict__ dnh, unsigned short* __restrict__ dnl,
                            const float* __restrict__ W, unsigned short* __restrict__ WTh,
                            unsigned short* __restrict__ WTl,
                            const float* __restrict__ sf, unsigned char* __restrict__ sf8T,
                            const float* __restrict__ T, const float* __restrict__ WT,
                            float* __restrict__ relwt,
                            u64* rowPk, u64* colPk, float* rowSm, float* colSm,
                            float* sq, int* cnt) {
    __shared__ float shf[64 * 65];    // 16.25KB: Tt for sfT/wrecT; first 256 = red for normalize
    int b = blockIdx.x;
    int t = threadIdx.x;
    if (b < 16384) {
        // ---- normalize + bf16 hi/lo split: dn[v][n][c] ----
        int row = b;                   // n*V + v
        int n = row >> 2, v = row & 3;
        float x = desc[(size_t)row * C_ + t];
        shf[t] = x * x;
        __syncthreads();
        for (int s = 128; s > 0; s >>= 1) {
            if (t < s) shf[t] += shf[t + s];
            __syncthreads();
        }
        float inv = 1.0f / fmaxf(sqrtf(shf[0]), 1e-12f);
        float y = x * inv;
        size_t o = ((size_t)v * N_ + n) * C_ + t;
        unsigned short h = f2bf(y);
        dnh[o] = h;
        dnl[o] = f2bf(y - bf2f(h));
    } else if (b < 17408) {
        // ---- sf8T[v][c][n] = fp8(sf[n][v][c]) ----
        int idx = b - 16384;
        int n0 = (idx & 63) * 64, c0 = ((idx >> 6) & 3) * 64, v = idx >> 8;
        int nr = t >> 2, cq = (t & 3) * 16;
        const float* src = sf + ((size_t)(n0 + nr) * V_ + v) * C_ + c0 + cq;
        for (int u = 0; u < 16; ++u) shf[(cq + u) * 65 + nr] = src[u];
        __syncthreads();
        int cr = t >> 2, nq = (t & 3) * 16;
        unsigned int wb[4];
#pragma unroll
        for (int g = 0; g < 4; ++g) {
            const float* p = shf + cr * 65 + nq + g * 4;
            wb[g] = pk4fp8(p[0], p[1], p[2], p[3]);
        }
        unsigned char* dst = sf8T + ((size_t)v * C_ + c0 + cr) * N_ + n0 + nq;
        *(uint4*)dst = make_uint4(wb[0], wb[1], wb[2], wb[3]);
    } else if (b < 17424) {
        // ---- WT[c][k] = W_rec[k][c], hi/lo bf16 split ----
        int idx = b - 17408;
        int k0 = (idx & 3) * 64, c0 = (idx >> 2) * 64;
        int kr = t >> 2, cq = (t & 3) * 16;
        const float* src = W + (size_t)(k0 + kr) * C_ + c0 + cq;
        for (int u = 0; u < 16; ++u) shf[(cq + u) * 65 + kr] = src[u];
        __syncthreads();
        int cr = t >> 2, kq = (t & 3) * 16;
        unsigned short th[16] __attribute__((aligned(16)));
        unsigned short tl[16] __attribute__((aligned(16)));
        for (int u = 0; u < 16; ++u) {
            float x = shf[cr * 65 + kq + u];
            unsigned short h = f2bf(x);
            th[u] = h; tl[u] = f2bf(x - bf2f(h));
        }
        size_t o = (size_t)(c0 + cr) * C_ + k0 + kq;
        *(uint4*)(WTh + o) = *(const uint4*)th;
        *(uint4*)(WTh + o + 8) = *(const uint4*)(th + 8);
        *(uint4*)(WTl + o) = *(const uint4*)tl;
        *(uint4*)(WTl + o + 8) = *(const uint4*)(tl + 8);
    } else if (b < 17440) {
        // ---- relWT[p][c], p = i*4+j ----
        int p = b - 17424; int i = p >> 2, j = p & 3;
        if (i == j) return;
        float acc = 0.f;
        for (int k = 0; k < 16; ++k) acc += T[i * 16 + k] * WT[(size_t)k * C_ + t];
        for (int k = 0; k < 16; ++k) acc += T[j * 16 + k] * WT[(size_t)(16 + k) * C_ + t];
        relwt[(size_t)p * C_ + t] = acc;
    } else {
        // ---- zero stats (all 6 slots) + pair accumulators ----
        int idx = (b - 17440) * 256 + t;   // 0..24575
        rowPk[idx] = 0ull; colPk[idx] = 0ull;
        rowSm[idx] = 0.f;  colSm[idx] = 0.f;
        if (idx < 16) { sq[idx] = 0.f; cnt[idx] = 0; }
    }
}

// ---- R = dn @ W_rec via split-bf16 MFMA; block 128x128, wave 64x64 ----
__global__ __launch_bounds__(256) void rmatmul_k(
    const unsigned short* __restrict__ Ah, const unsigned short* __restrict__ Al,
    const unsigned short* __restrict__ Bh, const unsigned short* __restrict__ Bl,
    float* __restrict__ R) {
    __shared__ unsigned short smem[4 * 128 * 40];
    unsigned short* sAh = smem;
    unsigned short* sAl = sAh + 128 * 40;
    unsigned short* sBh = sAl + 128 * 40;
    unsigned short* sBl = sBh + 128 * 40;
    int tid = threadIdx.x;
    int c0 = blockIdx.x * 128, m0 = blockIdx.y * 128;
    int w = tid >> 6, l = tid & 63, wm = w & 1, wn = w >> 1;
    int mr = l & 15, q = l >> 4;
    f32x4 acc[4][4];
#pragma unroll
    for (int a = 0; a < 4; ++a)
#pragma unroll
        for (int b = 0; b < 4; ++b)
#pragma unroll
            for (int u = 0; u < 4; ++u) acc[a][b][u] = 0.f;
    int r = tid >> 1, h = (tid & 1) * 16;
    for (int k0 = 0; k0 < C_; k0 += 32) {
        size_t ga = (size_t)(m0 + r) * C_ + k0 + h;
        size_t gb = (size_t)(c0 + r) * C_ + k0 + h;
        uint4 a0 = *(const uint4*)(Ah + ga);
        uint4 a1 = *(const uint4*)(Ah + ga + 8);
        uint4 a2 = *(const uint4*)(Al + ga);
        uint4 a3 = *(const uint4*)(Al + ga + 8);
        uint4 b0 = *(const uint4*)(Bh + gb);
        uint4 b1 = *(const uint4*)(Bh + gb + 8);
        uint4 b2 = *(const uint4*)(Bl + gb);
        uint4 b3 = *(const uint4*)(Bl + gb + 8);
        *(uint4*)(sAh + r * 40 + h)     = a0;
        *(uint4*)(sAh + r * 40 + h + 8) = a1;
        *(uint4*)(sAl + r * 40 + h)     = a2;
        *(uint4*)(sAl + r * 40 + h + 8) = a3;
        *(uint4*)(sBh + r * 40 + h)     = b0;
        *(uint4*)(sBh + r * 40 + h + 8) = b1;
        *(uint4*)(sBl + r * 40 + h)     = b2;
        *(uint4*)(sBl + r * 40 + h + 8) = b3;
        __syncthreads();
        bf16x8 fah[4], fal[4], fbh[4], fbl[4];
#pragma unroll
        for (int ti = 0; ti < 4; ++ti) {
            int row = wm * 64 + ti * 16 + mr;
            fah[ti] = *(const bf16x8*)(sAh + row * 40 + q * 8);
            fal[ti] = *(const bf16x8*)(sAl + row * 40 + q * 8);
        }
#pragma unroll
        for (int tj = 0; tj < 4; ++tj) {
            int row = wn * 64 + tj * 16 + mr;
            fbh[tj] = *(const bf16x8*)(sBh + row * 40 + q * 8);
            fbl[tj] = *(const bf16x8*)(sBl + row * 40 + q * 8);
        }
#pragma unroll
        for (int ti = 0; ti < 4; ++ti)
#pragma unroll
            for (int tj = 0; tj < 4; ++tj) acc[ti][tj] = mfma16(fah[ti], fbh[tj], acc[ti][tj]);
#pragma unroll
        for (int ti = 0; ti < 4; ++ti)
#pragma unroll
            for (int tj = 0; tj < 4; ++tj) acc[ti][tj] = mfma16(fah[ti], fbl[tj], acc[ti][tj]);
#pragma unroll
        for (int ti = 0; ti < 4; ++ti)
#pragma unroll
            for (int tj = 0; tj < 4; ++tj) acc[ti][tj] = mfma16(fal[ti], fbh[tj], acc[ti][tj]);
        __syncthreads();
    }
#pragma unroll
    for (int ti = 0; ti < 4; ++ti)
#pragma unroll
        for (int tj = 0; tj < 4; ++tj) {
            int c = c0 + wn * 64 + tj * 16 + mr;
#pragma unroll
            for (int rg = 0; rg < 4; ++rg) {
                int m = m0 + wm * 64 + ti * 16 + q * 4 + rg;
                R[(size_t)m * C_ + c] = acc[ti][tj][rg];
            }
        }
}

// ---- sim: 64x64 tile, split-bf16 3-term, reg-prefetched staging,
//      exp-once, fp8 E/ET. Stats fused into pack passes; partial reduce via
//      4-lane shuffles. grid (64, 64, 3) ----
__global__ __launch_bounds__(256) void sim_mfma_k(
    const unsigned short* __restrict__ dnh, const unsigned short* __restrict__ dnl,
    int ipack, int jpack, unsigned char* __restrict__ E8b, unsigned char* __restrict__ ET8b,
    u64* __restrict__ rowPkB, float* __restrict__ rowSmB,
    u64* __restrict__ colPkB, float* __restrict__ colSmB, int slotBase) {
    __shared__ unsigned char smem[36864];
    unsigned short* sAh = (unsigned short*)smem;          // [64][72]
    unsigned short* sAl = sAh + 64 * 72;
    unsigned short* sBh = sAl + 64 * 72;
    unsigned short* sBl = sBh + 64 * 72;
    float* S = (float*)smem;                               // [64][65] alias, holds expS

    int zp = blockIdx.z;
    int iv = (ipack >> (8 * zp)) & 15;
    int jv = (jpack >> (8 * zp)) & 15;
    const unsigned short* Ahi = dnh + (size_t)iv * N_ * C_;
    const unsigned short* Alo = dnl + (size_t)iv * N_ * C_;
    const unsigned short* Bhi = dnh + (size_t)jv * N_ * C_;
    const unsigned short* Blo = dnl + (size_t)jv * N_ * C_;
    unsigned char* E8  = E8b  + (size_t)zp * N_ * N_;
    unsigned char* ET8 = ET8b + (size_t)zp * N_ * N_;
    int slot = slotBase + zp;
    u64*   rowPk = rowPkB + (size_t)slot * N_;
    float* rowSm = rowSmB + (size_t)slot * N_;
    u64*   colPk = colPkB + (size_t)slot * N_;
    float* colSm = colSmB + (size_t)slot * N_;

    int tid = threadIdx.x;
    int m0 = blockIdx.y * 64, n0 = blockIdx.x * 64;
    int w = tid >> 6, l = tid & 63;
    int wm = w & 1, wn = w >> 1;
    int mr = l & 15, q = l >> 4;

    f32x4 acc[2][2];
#pragma unroll
    for (int a = 0; a < 2; ++a)
#pragma unroll
        for (int b = 0; b < 2; ++b)
#pragma unroll
            for (int u = 0; u < 4; ++u) acc[a][b][u] = 0.f;

    int r = tid >> 2;
    int k8 = (tid & 3) * 8;
    const unsigned short* gAh = Ahi + (size_t)(m0 + r) * C_ + k8;
    const unsigned short* gAl = Alo + (size_t)(m0 + r) * C_ + k8;
    const unsigned short* gBh = Bhi + (size_t)(n0 + r) * C_ + k8;
    const unsigned short* gBl = Blo + (size_t)(n0 + r) * C_ + k8;

    uint4 a0 = *(const uint4*)(gAh);
    uint4 a1 = *(const uint4*)(gAh + 32);
    uint4 a2 = *(const uint4*)(gAl);
    uint4 a3 = *(const uint4*)(gAl + 32);
    uint4 b0 = *(const uint4*)(gBh);
    uint4 b1 = *(const uint4*)(gBh + 32);
    uint4 b2 = *(const uint4*)(gBl);
    uint4 b3 = *(const uint4*)(gBl + 32);

    for (int k0 = 0; k0 < C_; k0 += 64) {
        *(uint4*)(sAh + r * 72 + k8)      = a0;
        *(uint4*)(sAh + r * 72 + k8 + 32) = a1;
        *(uint4*)(sAl + r * 72 + k8)      = a2;
        *(uint4*)(sAl + r * 72 + k8 + 32) = a3;
        *(uint4*)(sBh + r * 72 + k8)      = b0;
        *(uint4*)(sBh + r * 72 + k8 + 32) = b1;
        *(uint4*)(sBl + r * 72 + k8)      = b2;
        *(uint4*)(sBl + r * 72 + k8 + 32) = b3;
        __syncthreads();
        int kn = k0 + 64;
        if (kn < C_) {      // prefetch next K-chunk; vmcnt awaited at next staging write
            a0 = *(const uint4*)(gAh + kn);
            a1 = *(const uint4*)(gAh + kn + 32);
            a2 = *(const uint4*)(gAl + kn);
            a3 = *(const uint4*)(gAl + kn + 32);
            b0 = *(const uint4*)(gBh + kn);
            b1 = *(const uint4*)(gBh + kn + 32);
            b2 = *(const uint4*)(gBl + kn);
            b3 = *(const uint4*)(gBl + kn + 32);
        }
#pragma unroll
        for (int ks = 0; ks < 64; ks += 32) {
            bf16x8 ah[2], al[2], bh[2], bl[2];
#pragma unroll
            for (int ti = 0; ti < 2; ++ti) {
                int mrow = wm * 32 + ti * 16 + mr;
                ah[ti] = *(const bf16x8*)(sAh + mrow * 72 + ks + q * 8);
                al[ti] = *(const bf16x8*)(sAl + mrow * 72 + ks + q * 8);
            }
#pragma unroll
            for (int tj = 0; tj < 2; ++tj) {
                int nrow = wn * 32 + tj * 16 + mr;
                bh[tj] = *(const bf16x8*)(sBh + nrow * 72 + ks + q * 8);
                bl[tj] = *(const bf16x8*)(sBl + nrow * 72 + ks + q * 8);
            }
#pragma unroll
            for (int ti = 0; ti < 2; ++ti)
#pragma unroll
                for (int tj = 0; tj < 2; ++tj) {
                    acc[ti][tj] = mfma16(ah[ti], bh[tj], acc[ti][tj]);
                    acc[ti][tj] = mfma16(ah[ti], bl[tj], acc[ti][tj]);
                    acc[ti][tj] = mfma16(al[ti], bh[tj], acc[ti][tj]);
                }
        }
        __syncthreads();
    }

    // ---- epilogue: exp once into LDS ----
#pragma unroll
    for (int ti = 0; ti < 2; ++ti)
#pragma unroll
        for (int tj = 0; tj < 2; ++tj)
#pragma unroll
            for (int rg = 0; rg < 4; ++rg)
                S[(wm * 32 + ti * 16 + q * 4 + rg) * 65 + wn * 32 + tj * 16 + mr] =
                    __expf(acc[ti][tj][rg]);
    __syncthreads();

    // FUSED pass 1: E store (fp8, row-major) + row max/argmax/sum.
    {
        int rr = tid >> 2, cq = (tid & 3) * 16;
        const float* p = S + rr * 65 + cq;
        float mx = -1e30f; int ag = 0; float sm = 0.f;
        unsigned int wb[4];
#pragma unroll
        for (int g = 0; g < 4; ++g) {
            float f0 = p[g * 4 + 0], f1 = p[g * 4 + 1];
            float f2 = p[g * 4 + 2], f3 = p[g * 4 + 3];
            sm += (f0 + f1) + (f2 + f3);
            if (f0 > mx) { mx = f0; ag = cq + g * 4 + 0; }
            if (f1 > mx) { mx = f1; ag = cq + g * 4 + 1; }
            if (f2 > mx) { mx = f2; ag = cq + g * 4 + 2; }
            if (f3 > mx) { mx = f3; ag = cq + g * 4 + 3; }
            wb[g] = pk4fp8(f0, f1, f2, f3);
        }
        *(uint4*)(E8 + (size_t)(m0 + rr) * N_ + n0 + cq) = make_uint4(wb[0], wb[1], wb[2], wb[3]);
#pragma unroll
        for (int d = 1; d <= 2; d <<= 1) {
            float omx = __shfl_xor(mx, d);
            int   oag = __shfl_xor(ag, d);
            float osm = __shfl_xor(sm, d);
            sm += osm;
            if (omx > mx || (omx == mx && oag < ag)) { mx = omx; ag = oag; }
        }
        if ((tid & 3) == 0) {
            u64 pk = ((u64)__float_as_uint(mx) << 32) | (u64)(0xFFFFFFFFu - (unsigned)(n0 + ag));
            atomicMax(rowPk + m0 + rr, pk);
            atomicAdd(rowSm + m0 + rr, sm);
        }
    }
    // FUSED pass 2: ET store (fp8, row-major in n) + col max/argmax/sum.
    {
        int cc = tid >> 2, mq = (tid & 3) * 16;
        float mx = -1e30f; int ag = 0; float sm = 0.f;
        unsigned int wb[4];
#pragma unroll
        for (int g = 0; g < 4; ++g) {
            float f0 = S[(mq + g * 4 + 0) * 65 + cc];
            float f1 = S[(mq + g * 4 + 1) * 65 + cc];
            float f2 = S[(mq + g * 4 + 2) * 65 + cc];
            float f3 = S[(mq + g * 4 + 3) * 65 + cc];
            sm += (f0 + f1) + (f2 + f3);
            if (f0 > mx) { mx = f0; ag = mq + g * 4 + 0; }
            if (f1 > mx) { mx = f1; ag = mq + g * 4 + 1; }
            if (f2 > mx) { mx = f2; ag = mq + g * 4 + 2; }
            if (f3 > mx) { mx = f3; ag = mq + g * 4 + 3; }
            wb[g] = pk4fp8(f0, f1, f2, f3);
        }
        *(uint4*)(ET8 + (size_t)(n0 + cc) * N_ + m0 + mq) = make_uint4(wb[0], wb[1], wb[2], wb[3]);
#pragma unroll
        for (int d = 1; d <= 2; d <<= 1) {
            float omx = __shfl_xor(mx, d);
            int   oag = __shfl_xor(ag, d);
            float osm = __shfl_xor(sm, d);
            sm += osm;
            if (omx > mx || (omx == mx && oag < ag)) { mx = omx; ag = oag; }
        }
        if ((tid & 3) == 0) {
            u64 pk = ((u64)__float_as_uint(mx) << 32) | (u64)(0xFFFFFFFFu - (unsigned)(m0 + ag));
            atomicMax(colPk + n0 + cc, pk);
            atomicAdd(colSm + n0 + cc, sm);
        }
    }
}

// ---- pass2 v3: fp8 GEMM 64m x 128c, K-chunk 64, pitch-80 LDS, fused loss ----
// grid: (128, 6): bx -> ct = bx&1 (c half), mt = bx>>1; by -> d = by&1, zp = by>>1
__global__ __launch_bounds__(256) void p2_k(
    const unsigned char* __restrict__ E8b, const unsigned char* __restrict__ ET8b,
    const unsigned char* __restrict__ sf8T, int ipack, int jpack,
    const u64* __restrict__ rowPkB, const float* __restrict__ rowSmB,
    const u64* __restrict__ colPkB, const float* __restrict__ colSmB, int slotBase,
    const float* __restrict__ R, const float* __restrict__ relwt,
    float* __restrict__ pairSq, int* __restrict__ pairCnt) {
    __shared__ unsigned char sA[64 * 80];    // 64 m-rows x 64 k + pad
    __shared__ unsigned char sB[128 * 80];   // 128 c-rows x 64 k + pad
    __shared__ float red[256];
    __shared__ int   mutS[64];
    __shared__ float invS[64];
    int tid = threadIdx.x;
    int ct = blockIdx.x & 1, mt = blockIdx.x >> 1;
    int d = blockIdx.y & 1, zp = blockIdx.y >> 1;
    int iv = (ipack >> (8 * zp)) & 15;
    int jv = (jpack >> (8 * zp)) & 15;
    int slot = slotBase + zp;
    const unsigned char* A = (d ? ET8b : E8b) + (size_t)zp * N_ * N_;
    const unsigned char* B = sf8T + (size_t)(d ? iv : jv) * C_ * N_;
    const u64* faPk = (d ? colPkB : rowPkB) + (size_t)slot * N_;
    const u64* baPk = (d ? rowPkB : colPkB) + (size_t)slot * N_;
    const float* sumE = (d ? colSmB : rowSmB) + (size_t)slot * N_;
    const float* Rr = R + (size_t)(d ? jv : iv) * N_ * C_;
    int pid = d ? (jv * 4 + iv) : (iv * 4 + jv);
    int c0 = ct * 128, m0 = mt * 64;
    int w = tid >> 6, l = tid & 63, wm = w & 1, wn = w >> 1;
    int mr = l & 15, q = l >> 4;
    if (tid < 64) {
        int y = m0 + tid;
        unsigned faIdx = 0xFFFFFFFFu - (unsigned)(faPk[y] & 0xFFFFFFFFull);
        unsigned baIdx = 0xFFFFFFFFu - (unsigned)(baPk[faIdx] & 0xFFFFFFFFull);
        mutS[tid] = (baIdx == (unsigned)y) ? 1 : 0;
        invS[tid] = 1.0f / sumE[y];
    }
    f32x4 acc[2][4];
#pragma unroll
    for (int a = 0; a < 2; ++a)
#pragma unroll
        for (int b = 0; b < 4; ++b)
#pragma unroll
            for (int u = 0; u < 4; ++u) acc[a][b][u] = 0.f;

    int ra = tid >> 2, ka = (tid & 3) * 16;
    int rb = tid >> 1, kbb = (tid & 1) * 32;
    const unsigned char* Arow = A + (size_t)(m0 + ra) * N_ + ka;
    const unsigned char* Brow = B + (size_t)(c0 + rb) * N_ + kbb;
    uint4 pa  = *(const uint4*)(Arow);
    uint4 pb0 = *(const uint4*)(Brow);
    uint4 pb1 = *(const uint4*)(Brow + 16);
    for (int k0 = 0; k0 < N_; k0 += 64) {
        *(uint4*)(sA + ra * 80 + ka)       = pa;
        *(uint4*)(sB + rb * 80 + kbb)      = pb0;
        *(uint4*)(sB + rb * 80 + kbb + 16) = pb1;
        __syncthreads();
        int kn = k0 + 64;
        if (kn < N_) {
            pa  = *(const uint4*)(Arow + kn);
            pb0 = *(const uint4*)(Brow + kn);
            pb1 = *(const uint4*)(Brow + kn + 16);
        }
#pragma unroll
        for (int ksub = 0; ksub < 64; ksub += 32) {
            long af[2], bf[4];
#pragma unroll
            for (int ti = 0; ti < 2; ++ti)
                af[ti] = *(const long*)(sA + (wm * 32 + ti * 16 + mr) * 80 + ksub + q * 8);
#pragma unroll
            for (int tj = 0; tj < 4; ++tj)
                bf[tj] = *(const long*)(sB + (wn * 64 + tj * 16 + mr) * 80 + ksub + q * 8);
#pragma unroll
            for (int ti = 0; ti < 2; ++ti)
#pragma unroll
                for (int tj = 0; tj < 4; ++tj)
                    acc[ti][tj] = __builtin_amdgcn_mfma_f32_16x16x32_fp8_fp8(
                        af[ti], bf[tj], acc[ti][tj], 0, 0, 0);
        }
        __syncthreads();
    }
    const float* rw = relwt + (size_t)pid * C_;
    float local = 0.f;
#pragma unroll
    for (int ti = 0; ti < 2; ++ti)
#pragma unroll
        for (int tj = 0; tj < 4; ++tj) {
            int c = c0 + wn * 64 + tj * 16 + mr;
            float rwc = rw[c];
#pragma unroll
            for (int rg = 0; rg < 4; ++rg) {
                int ml = wm * 32 + ti * 16 + q * 4 + rg;
                if (mutS[ml]) {
                    int m = m0 + ml;
                    float soft = acc[ti][tj][rg] * invS[ml];
                    float dv = Rr[(size_t)m * C_ + c] + rwc - soft;
                    local += dv * dv;
                }
            }
        }
    red[tid] = local;
    __syncthreads();
    for (int s = 128; s > 0; s >>= 1) {
        if (tid < s) red[tid] += red[tid + s];
        __syncthreads();
    }
    if (tid == 0) {
        atomicAdd(pairSq + pid, red[0]);
        if (ct == 0) {
            int cnt = 0;
            for (int u = 0; u < 64; ++u) cnt += mutS[u];
            atomicAdd(pairCnt + pid, cnt);
        }
    }
}

// ---- final scalar combine ----
__global__ void final_k(const float* __restrict__ sq, const int* __restrict__ cnt,
                        float* __restrict__ out) {
    if (threadIdx.x == 0 && blockIdx.x == 0) {
        float loss = 0.f, count = 0.f;
        for (int p = 0; p < 16; ++p) {
            int i = p >> 2, j = p & 3;
            if (i == j) continue;
            float ns = (float)cnt[p];
            if (ns > 0.f) { loss += sq[p] / fmaxf(ns * (float)C_, 1.0f); count += 1.f; }
        }
        out[0] = (count > 0.f) ? loss / count : 0.f;
    }
}

extern "C" void kernel_launch(void* const* d_in, const int* in_sizes, int n_in,
                              void* d_out, int out_size, void* d_ws, size_t ws_size,
                              hipStream_t stream) {
    const float* desc = (const float*)d_in[0];
    const float* sf   = (const float*)d_in[1];
    const float* T    = (const float*)d_in[2];
    const float* Wrec = (const float*)d_in[3];
    const float* WT   = (const float*)d_in[4];
    float* out = (float*)d_out;
    char* ws = (char*)d_ws;

    float*          R     = (float*)(ws + OFF_R);
    unsigned short* dnh   = (unsigned short*)(ws + OFF_DNHI);
    unsigned short* dnl   = (unsigned short*)(ws + OFF_DNLO);
    unsigned char*  sf8T  = (unsigned char*)(ws + OFF_SFT);
    unsigned char*  E8b   = (unsigned char*)(ws + OFF_E);
    unsigned char*  ET8b  = (unsigned char*)(ws + OFF_ET);
    unsigned short* WTh   = (unsigned short*)(ws + OFF_WTH);
    unsigned short* WTl   = (unsigned short*)(ws + OFF_WTL);
    u64*   rowPk = (u64*)(ws + OFF_ROWPK);
    u64*   colPk = (u64*)(ws + OFF_COLPK);
    float* rowSm = (float*)(ws + OFF_ROWSM);
    float* colSm = (float*)(ws + OFF_COLSM);
    float* relwt = (float*)(ws + OFF_RELWT);
    float* pairSq = (float*)(ws + OFF_SQ);
    int*   pairCnt = (int*)(ws + OFF_CNT);

    // one fused preprocessing launch (was 5)
    fused_pre_k<<<17536, 256, 0, stream>>>(desc, dnh, dnl, Wrec, WTh, WTl,
                                           sf, sf8T, T, WT, relwt,
                                           rowPk, colPk, rowSm, colSm, pairSq, pairCnt);
    rmatmul_k<<<dim3(2, 128), 256, 0, stream>>>(dnh, dnl, WTh, WTl, R);

    // batch 0: pairs (0,1),(0,2),(0,3); batch 1: (1,2),(1,3),(2,3)
    const int ip[2] = { 0 | (0 << 8) | (0 << 16), 1 | (1 << 8) | (2 << 16) };
    const int jp[2] = { 1 | (2 << 8) | (3 << 16), 2 | (3 << 8) | (3 << 16) };
    for (int b = 0; b < 2; ++b) {
        sim_mfma_k<<<dim3(64, 64, 3), 256, 0, stream>>>(
            dnh, dnl, ip[b], jp[b], E8b, ET8b, rowPk, rowSm, colPk, colSm, b * 3);
        p2_k<<<dim3(128, 6), 256, 0, stream>>>(
            E8b, ET8b, sf8T, ip[b], jp[b], rowPk, rowSm, colPk, colSm, b * 3,
            R, relwt, pairSq, pairCnt);
    }
    final_k<<<1, 64, 0, stream>>>(pairSq, pairCnt, out);
}